// Round 7
// baseline (141.652 us; speedup 1.0000x reference)
//
#include <hip/hip_runtime.h>

#define NTOK 8192
#define DDIM 1024
#define NEXP 16
#define NPAIR 136   // E*(E+1)/2 pairs with e<=f
#define QPAD 264    // d-quarter stride in floats (256 + 8 pad): quarter bases
                    // hit banks {0,8,16,24} -> B-phase ds_read conflict-free
#define NBLK 2048   // fused blocks, 4 tokens each
#define NRED 64     // xred_gram blocks, 16-d chunk each

// ws layout (floats): gwT [16384] | slots [2048*1024] = 8 MB | G_part [64*136] | cnt (1 int)
#define WS_GWT  0
#define WS_SLOT 16384
#define WS_GP   (WS_SLOT + NBLK * DDIM)
#define WS_CNT  (WS_GP + NRED * NPAIR)

// ---------------------------------------------------------------------------
// Prep: transpose gate_w [16][1024] -> gwT4[d4][e] (float4 over d, expert-
// contiguous) so routing reads are fully coalesced. Zero the gram ticket.
// ---------------------------------------------------------------------------
__global__ __launch_bounds__(256) void moe_prep(
    const float* __restrict__ gate_w,
    float* __restrict__ ws)
{
    const int gid = blockIdx.x * 256 + threadIdx.x;   // 0..4095
    const int e = gid & 15;
    const int d4 = gid >> 4;                          // 0..255
    const float4* gw4 = (const float4*)gate_w;
    float4* gwT4 = (float4*)(ws + WS_GWT);
    gwT4[d4 * 16 + e] = gw4[e * 256 + d4];
    if (gid == 0) ((int*)ws)[WS_CNT] = 0;
}

// ---------------------------------------------------------------------------
// Fused: 2048 blocks x 256 thr, 4 tokens/block (LDS 16.9 KB -> 8 blocks/CU).
// A: x-tile -> LDS (quarter-padded layout); thread t owns d-cols 4t..4t+3 ->
//    x^2 partials in regs; slot store issued immediately (drains under B-D).
// B: wave = token; lane = (e, quarter). Quarter-padded xrow bases kill the
//    4-way bank conflict (SQ_LDS_BANK_CONFLICT 2.1M -> expect <0.6M).
// C: top2 scan, wave-uniform result (no D shuffles).
// D: wave writes its own token, coalesced float4 out, re rows L2-hot.
// ---------------------------------------------------------------------------
__global__ __launch_bounds__(256, 8) void moe_fused(
    const float* __restrict__ x,
    const float* __restrict__ gate_b,
    const float* __restrict__ sh,
    const float* __restrict__ re,
    float* __restrict__ out,
    float* __restrict__ ws)
{
    __shared__ __align__(16) float xt[4][4 * QPAD];   // 4224 B per token row

    const int t = threadIdx.x;
    const int b = blockIdx.x;
    const float4* gwT4 = (const float4*)(ws + WS_GWT);

    // ---- A: stage 4 token rows (quarter-padded), accumulate x^2 ----
    float4 ss = make_float4(0.f, 0.f, 0.f, 0.f);
    {
        const float4* x4 = (const float4*)x + (size_t)b * 1024;
        const int dst = 4 * t + 8 * (t >> 6);         // quarter-padded offset
        #pragma unroll
        for (int i = 0; i < 4; ++i) {
            float4 v = x4[i * 256 + t];
            *(float4*)&xt[i][dst] = v;
            ss.x = fmaf(v.x, v.x, ss.x);
            ss.y = fmaf(v.y, v.y, ss.y);
            ss.z = fmaf(v.z, v.z, ss.z);
            ss.w = fmaf(v.w, v.w, ss.w);
        }
    }
    // slot store early: no dependency until next dispatch; retires under B-D
    *(float4*)(ws + WS_SLOT + (size_t)b * DDIM + 4 * t) = ss;
    __syncthreads();

    const int lane = t & 63;
    const int wv = t >> 6;          // wave index == local token index
    const int e = lane & 15;
    const int qr = lane >> 4;       // d-quarter 0..3 (256 floats each)

    // ---- B: routing (wave wv computes all 16 logits for token wv) ----
    const float* xrow = &xt[wv][qr * QPAD];
    const float4* gt = gwT4 + qr * 64 * 16;
    float4 a4 = make_float4(0.f, 0.f, 0.f, 0.f);
    #pragma unroll 8
    for (int i = 0; i < 64; ++i) {
        float4 xv = *(const float4*)(xrow + 4 * i);  // bcast, conflict-free
        float4 gv = gt[i * 16 + e];                  // 256B contiguous / 16 lanes
        a4.x = fmaf(xv.x, gv.x, a4.x);
        a4.y = fmaf(xv.y, gv.y, a4.y);
        a4.z = fmaf(xv.z, gv.z, a4.z);
        a4.w = fmaf(xv.w, gv.w, a4.w);
    }
    float acc = (a4.x + a4.y) + (a4.z + a4.w);
    acc += __shfl_xor(acc, 16, 64);                  // merge quarter pairs
    acc += __shfl_xor(acc, 32, 64);                  // full 1024-d logit
    acc += gate_b[e];

    // ---- C: stable top2 scan (ascending j, strict > == lax.top_k ties) ----
    float v0 = -3.0e38f, v1 = -3.0e38f;
    int i0 = 0, i1 = 0;
    const int base = lane & 48;                      // stay in own quarter
    #pragma unroll
    for (int j = 0; j < NEXP; ++j) {
        float lv = __shfl(acc, base + j, 64);
        if (lv > v0)      { v1 = v0; i1 = i0; v0 = lv; i0 = j; }
        else if (lv > v1) { v1 = lv; i1 = j; }
    }
    float ex = __expf(v1 - v0);                      // softmax denom cancels
    float w0 = 1.f / (1.f + ex);
    float w1 = ex * w0;
    // (w0,i0,w1,i1) identical across the wave: no shuffles needed in D.

    // hoisted shared-expert column sum for combine slots
    float4 shs[4];
    {
        const float4* s0 = (const float4*)sh;
        const float4* s1 = (const float4*)(sh + DDIM);
        #pragma unroll
        for (int j = 0; j < 4; ++j) {
            float4 p = s0[lane + 64 * j];
            float4 s = s1[lane + 64 * j];
            shs[j] = make_float4(p.x + s.x, p.y + s.y, p.z + s.z, p.w + s.w);
        }
    }

    // ---- D: combine — wave wv writes token wv ----
    {
        const float4* r0 = (const float4*)(re + (size_t)i0 * DDIM);
        const float4* r1 = (const float4*)(re + (size_t)i1 * DDIM);
        float4* o = (float4*)(out + ((size_t)b * 4 + wv) * DDIM);
        #pragma unroll
        for (int j = 0; j < 4; ++j) {
            const int idx = lane + 64 * j;           // d-quarter j
            float4 xv = ((const float4*)&xt[wv][j * QPAD])[lane];
            float4 b0 = r0[idx];
            float4 b1 = r1[idx];
            float4 r;
            r.x = xv.x * (shs[j].x + w0 * b0.x + w1 * b1.x);
            r.y = xv.y * (shs[j].y + w0 * b0.y + w1 * b1.y);
            r.z = xv.z * (shs[j].z + w0 * b0.z + w1 * b1.z);
            r.w = xv.w * (shs[j].w + w0 * b0.w + w1 * b1.w);
            o[idx] = r;
        }
    }
}

// ---------------------------------------------------------------------------
// xred_gram (+ fused finalizer): 64 blocks x 256 thr. Block j owns d-chunk
// [16j, 16j+16).
// 1) Reduce 2048 slots for the chunk (32 strided float4 loads/thread).
// 2) LDS fold to s_loc[16].  3) Stage reT[16][16].
// 4) 136 pair-threads: 16-iter LDS partial Gram -> G_part[j] (agent stores).
// 5) Ticket: last of 64 blocks sums G_part (136 thr x 64 L2-hot loads, ~1us),
//    norms, clipped cosine mean. (Proven ticket pattern: store -> barrier
//    vmcnt drain -> RMW ticket -> acquire fence.)
// ---------------------------------------------------------------------------
__global__ __launch_bounds__(256) void moe_xred_gram(
    const float* __restrict__ re,
    float* __restrict__ ws,
    float* __restrict__ div_out)
{
    __shared__ float4 s4[64][4];
    __shared__ float s_loc[16];
    __shared__ float reT[16][16];   // [dd][e]
    __shared__ float Gs[NPAIR];
    __shared__ float nr[NEXP];
    __shared__ float lsum;
    __shared__ int   role;

    const int t = threadIdx.x;
    const int j = blockIdx.x;       // d-chunk index
    const int c = t & 3;            // float4 col within chunk
    const int r = t >> 2;           // 0..63
    int* cnt = (int*)ws + WS_CNT;

    // 1) slot reduction: thread (c,r) sums slots b2 = r + 64k, k=0..31
    {
        const float4* sl4 = (const float4*)(ws + WS_SLOT);
        const size_t colbase = (size_t)4 * j + c;
        float4 acc = make_float4(0.f, 0.f, 0.f, 0.f);
        #pragma unroll 8
        for (int k = 0; k < 32; ++k) {
            float4 v = sl4[(size_t)(r + 64 * k) * 256 + colbase];
            acc.x += v.x; acc.y += v.y; acc.z += v.z; acc.w += v.w;
        }
        s4[r][c] = acc;
    }
    // 3) stage reT chunk (all 256 threads: e = t>>4, dd = t&15)
    {
        const int e = t >> 4, dd = t & 15;
        reT[dd][e] = re[(size_t)e * DDIM + 16 * j + dd];
    }
    __syncthreads();

    // 2) finish chunk reduction: 4 threads fold 64 partials each
    if (t < 4) {
        float4 a = s4[0][t];
        for (int rr = 1; rr < 64; ++rr) {
            float4 v = s4[rr][t];
            a.x += v.x; a.y += v.y; a.z += v.z; a.w += v.w;
        }
        s_loc[4 * t + 0] = a.x;
        s_loc[4 * t + 1] = a.y;
        s_loc[4 * t + 2] = a.z;
        s_loc[4 * t + 3] = a.w;
    }
    __syncthreads();

    // 4) partial Gram over this 16-d chunk -> G_part (agent-visible stores)
    if (t < NPAIR) {
        int pe = 0, rem = t;
        while (rem >= NEXP - pe) { rem -= NEXP - pe; ++pe; }
        const int pf = pe + rem;
        float a = 0.f;
        #pragma unroll
        for (int dd = 0; dd < 16; ++dd)
            a += s_loc[dd] * reT[dd][pe] * reT[dd][pf];
        __hip_atomic_store(ws + WS_GP + j * NPAIR + t, a,
                           __ATOMIC_RELAXED, __HIP_MEMORY_SCOPE_AGENT);
    }

    // 5) ticket; last block finalizes the loss
    __syncthreads();   // vmcnt(0): G_part stores globally visible before ticket
    if (t == 0) {
        int k = atomicAdd(cnt, 1);
        role = (k == NRED - 1);
    }
    __syncthreads();
    if (!role) return;
    __builtin_amdgcn_fence(__ATOMIC_ACQUIRE, "agent");

    if (t == 0) lsum = 0.f;
    if (t < NPAIR) {
        const float* gp = ws + WS_GP;
        float g = 0.f;
        #pragma unroll 8
        for (int jj = 0; jj < NRED; ++jj) g += gp[jj * NPAIR + t];
        Gs[t] = g;
    }
    __syncthreads();
    if (t < NEXP) {
        int idx = t * NEXP - (t * (t - 1)) / 2;   // diagonal (t,t)
        nr[t] = fmaxf(sqrtf(Gs[idx]), 1e-8f);
    }
    __syncthreads();
    if (t < NPAIR) {
        int pe = 0, rem = t;
        while (rem >= NEXP - pe) { rem -= NEXP - pe; ++pe; }
        const int pf = pe + rem;
        if (pe != pf) {
            float sim = Gs[t] / (nr[pe] * nr[pf]);
            sim = fminf(1.f, fmaxf(-1.f, sim));
            atomicAdd(&lsum, 2.f * sim);          // LDS atomic, 120 adds
        }
    }
    __syncthreads();
    if (t == 0) *div_out = lsum / (float)(NEXP * (NEXP - 1)) * 0.1f;
}

extern "C" void kernel_launch(void* const* d_in, const int* in_sizes, int n_in,
                              void* d_out, int out_size, void* d_ws, size_t ws_size,
                              hipStream_t stream) {
    const float* x  = (const float*)d_in[0];
    const float* gw = (const float*)d_in[1];
    const float* gb = (const float*)d_in[2];
    const float* sh = (const float*)d_in[3];
    const float* re = (const float*)d_in[4];
    float* out = (float*)d_out;
    float* ws = (float*)d_ws;   // needs ~8.5 MB (arena 256 MiB)

    moe_prep<<<16, 256, 0, stream>>>(gw, ws);
    moe_fused<<<NBLK, 256, 0, stream>>>(x, gb, sh, re, out, ws);
    moe_xred_gram<<<NRED, 256, 0, stream>>>(re, ws, out + (size_t)NTOK * DDIM);
}

// Round 8
// 134.426 us; speedup vs baseline: 1.0538x; 1.0538x over previous
//
#include <hip/hip_runtime.h>

#define NTOK 8192
#define DDIM 1024
#define NEXP 16
#define NPAIR 136   // E*(E+1)/2 pairs with e<=f
#define QPAD 264    // d-quarter stride in floats (256 + 8 pad)
#define NBLK 2048   // fused blocks, 4 tokens each
#define NRED 64     // xred_gram blocks, 16-d chunk each

// ws layout (floats): slots [2048*1024] = 8 MB | G_part [64*136]
#define WS_SLOT 0
#define WS_GP   (NBLK * DDIM)

// ---------------------------------------------------------------------------
// Fused: 2048 blocks x 256 thr, 4 tokens/block, 8 blocks/CU.
// A: x-tile -> LDS (quarter-padded); thread t owns d-cols 4t..4t+3 -> x^2
//    partials kept in regs until kernel end (no early-store vmcnt stall).
// B: ROUTER, register-cached gate rows. wave = d-quarter, lane = (e, sub):
//    each gate float4 is loaded ONCE and used for all 4 tokens (gate L2
//    traffic 512 MB -> 128 MB vs R7; 64 -> 16 gate loads/thread). Sub-
//    staggered i order keeps LDS reads bank-conflict-free. Partial logits
//    reduced: shfl_xor over subs, 1 KB LDS hop across quarters.
// C: top2 scan (wave-uniform result, token wv per wave).
// D: combine — wave wv writes token wv, coalesced float4 out, re L2-hot.
// E: x^2 slot store, fire-and-forget (dispatch boundary = release).
// ---------------------------------------------------------------------------
__global__ __launch_bounds__(256, 8) void moe_fused(
    const float* __restrict__ x,
    const float* __restrict__ gate_w,
    const float* __restrict__ gate_b,
    const float* __restrict__ sh,
    const float* __restrict__ re,
    float* __restrict__ out,
    float* __restrict__ ws)
{
    __shared__ __align__(16) float xt[4][4 * QPAD];   // 16.9 KB
    __shared__ float lg[4][4][16];                    // [tok][quarter][e] 1 KB

    const int t = threadIdx.x;
    const int b = blockIdx.x;

    // ---- A: stage 4 token rows (quarter-padded), accumulate x^2 ----
    float4 ss = make_float4(0.f, 0.f, 0.f, 0.f);
    {
        const float4* x4 = (const float4*)x + (size_t)b * 1024;
        const int dst = 4 * t + 8 * (t >> 6);         // quarter-padded offset
        #pragma unroll
        for (int i = 0; i < 4; ++i) {
            float4 v = x4[i * 256 + t];
            *(float4*)&xt[i][dst] = v;
            ss.x = fmaf(v.x, v.x, ss.x);
            ss.y = fmaf(v.y, v.y, ss.y);
            ss.z = fmaf(v.z, v.z, ss.z);
            ss.w = fmaf(v.w, v.w, ss.w);
        }
    }
    __syncthreads();

    const int lane = t & 63;
    const int wv = t >> 6;          // wave index == d-quarter == local token
    const int e = lane & 15;
    const int sub = lane >> 4;      // 64-d sub-chunk within the quarter

    // ---- B: router with register-cached gate fragments ----
    // lane covers gate_w[e][wv*256 + sub*64 .. +64), reused for 4 tokens.
    const float4* gt = (const float4*)gate_w + (size_t)e * 256 + wv * 64 + sub * 16;
    const float* xq = &xt[0][wv * QPAD + sub * 64];   // token stride 4*QPAD
    float4 a0 = make_float4(0.f, 0.f, 0.f, 0.f), a1 = a0, a2 = a0, a3 = a0;
    #pragma unroll
    for (int ii = 0; ii < 16; ++ii) {
        const int i = (ii + 2 * sub) & 15;            // bank-stagger by sub
        float4 gv = gt[i];
        const float* xp = xq + 4 * i;
        float4 x0 = *(const float4*)(xp);
        float4 x1 = *(const float4*)(xp + 4 * QPAD);
        float4 x2 = *(const float4*)(xp + 8 * QPAD);
        float4 x3 = *(const float4*)(xp + 12 * QPAD);
        a0.x = fmaf(gv.x, x0.x, a0.x); a0.y = fmaf(gv.y, x0.y, a0.y);
        a0.z = fmaf(gv.z, x0.z, a0.z); a0.w = fmaf(gv.w, x0.w, a0.w);
        a1.x = fmaf(gv.x, x1.x, a1.x); a1.y = fmaf(gv.y, x1.y, a1.y);
        a1.z = fmaf(gv.z, x1.z, a1.z); a1.w = fmaf(gv.w, x1.w, a1.w);
        a2.x = fmaf(gv.x, x2.x, a2.x); a2.y = fmaf(gv.y, x2.y, a2.y);
        a2.z = fmaf(gv.z, x2.z, a2.z); a2.w = fmaf(gv.w, x2.w, a2.w);
        a3.x = fmaf(gv.x, x3.x, a3.x); a3.y = fmaf(gv.y, x3.y, a3.y);
        a3.z = fmaf(gv.z, x3.z, a3.z); a3.w = fmaf(gv.w, x3.w, a3.w);
    }
    float r0 = (a0.x + a0.y) + (a0.z + a0.w);
    float r1 = (a1.x + a1.y) + (a1.z + a1.w);
    float r2 = (a2.x + a2.y) + (a2.z + a2.w);
    float r3 = (a3.x + a3.y) + (a3.z + a3.w);
    // sum over the 4 subs (lanes 16 apart share e)
    r0 += __shfl_xor(r0, 16, 64); r0 += __shfl_xor(r0, 32, 64);
    r1 += __shfl_xor(r1, 16, 64); r1 += __shfl_xor(r1, 32, 64);
    r2 += __shfl_xor(r2, 16, 64); r2 += __shfl_xor(r2, 32, 64);
    r3 += __shfl_xor(r3, 16, 64); r3 += __shfl_xor(r3, 32, 64);
    if (lane < 16) {                // quarter-partial logits -> LDS
        lg[0][wv][lane] = r0;
        lg[1][wv][lane] = r1;
        lg[2][wv][lane] = r2;
        lg[3][wv][lane] = r3;
    }
    __syncthreads();
    // wave wv assembles token wv's 16 logits (every lane holds logit e)
    float lv = ((lg[wv][0][e] + lg[wv][1][e]) + (lg[wv][2][e] + lg[wv][3][e]))
             + gate_b[e];

    // ---- C: stable top2 scan (ascending j, strict > == lax.top_k ties) ----
    float v0 = -3.0e38f, v1 = -3.0e38f;
    int i0 = 0, i1 = 0;
    const int base = lane & 48;                      // sources within own sub
    #pragma unroll
    for (int j = 0; j < NEXP; ++j) {
        float lj = __shfl(lv, base + j, 64);
        if (lj > v0)      { v1 = v0; i1 = i0; v0 = lj; i0 = j; }
        else if (lj > v1) { v1 = lj; i1 = j; }
    }
    float ex = __expf(v1 - v0);                      // softmax denom cancels
    float w0 = 1.f / (1.f + ex);
    float w1 = ex * w0;
    // (w0,i0,w1,i1) identical across the wave: no shuffles needed in D.

    // hoisted shared-expert column sum for combine slots
    float4 shs[4];
    {
        const float4* s0 = (const float4*)sh;
        const float4* s1 = (const float4*)(sh + DDIM);
        #pragma unroll
        for (int j = 0; j < 4; ++j) {
            float4 p = s0[lane + 64 * j];
            float4 s = s1[lane + 64 * j];
            shs[j] = make_float4(p.x + s.x, p.y + s.y, p.z + s.z, p.w + s.w);
        }
    }

    // ---- D: combine — wave wv writes token wv ----
    {
        const float4* r0p = (const float4*)(re + (size_t)i0 * DDIM);
        const float4* r1p = (const float4*)(re + (size_t)i1 * DDIM);
        float4* o = (float4*)(out + ((size_t)b * 4 + wv) * DDIM);
        #pragma unroll
        for (int j = 0; j < 4; ++j) {
            const int idx = lane + 64 * j;           // d-quarter j
            float4 xv = ((const float4*)&xt[wv][j * QPAD])[lane];
            float4 b0 = r0p[idx];
            float4 b1 = r1p[idx];
            float4 r;
            r.x = xv.x * (shs[j].x + w0 * b0.x + w1 * b1.x);
            r.y = xv.y * (shs[j].y + w0 * b0.y + w1 * b1.y);
            r.z = xv.z * (shs[j].z + w0 * b0.z + w1 * b1.z);
            r.w = xv.w * (shs[j].w + w0 * b0.w + w1 * b1.w);
            o[idx] = r;
        }
    }

    // ---- E: x^2 partial -> private slot (fire-and-forget) ----
    *(float4*)(ws + WS_SLOT + (size_t)b * DDIM + 4 * t) = ss;
}

// ---------------------------------------------------------------------------
// xred_gram: 64 blocks x 256 thr. Block j owns d-chunk [16j, 16j+16).
// 1) Reduce 2048 slots for the chunk (32 strided float4 loads/thread).
// 2) LDS fold to s_loc[16].  3) Stage reT[16][16].
// 4) 136 pair-threads: 16-iter LDS partial Gram -> G_part[j].
// ---------------------------------------------------------------------------
__global__ __launch_bounds__(256) void moe_xred_gram(
    const float* __restrict__ re,
    float* __restrict__ ws)
{
    __shared__ float4 s4[64][4];
    __shared__ float s_loc[16];
    __shared__ float reT[16][16];   // [dd][e]

    const int t = threadIdx.x;
    const int j = blockIdx.x;       // d-chunk index
    const int c = t & 3;            // float4 col within chunk
    const int r = t >> 2;           // 0..63

    {
        const float4* sl4 = (const float4*)(ws + WS_SLOT);
        const size_t colbase = (size_t)4 * j + c;
        float4 acc = make_float4(0.f, 0.f, 0.f, 0.f);
        #pragma unroll 8
        for (int k = 0; k < 32; ++k) {
            float4 v = sl4[(size_t)(r + 64 * k) * 256 + colbase];
            acc.x += v.x; acc.y += v.y; acc.z += v.z; acc.w += v.w;
        }
        s4[r][c] = acc;
    }
    {
        const int e = t >> 4, dd = t & 15;
        reT[dd][e] = re[(size_t)e * DDIM + 16 * j + dd];
    }
    __syncthreads();

    if (t < 4) {
        float4 a = s4[0][t];
        for (int rr = 1; rr < 64; ++rr) {
            float4 v = s4[rr][t];
            a.x += v.x; a.y += v.y; a.z += v.z; a.w += v.w;
        }
        s_loc[4 * t + 0] = a.x;
        s_loc[4 * t + 1] = a.y;
        s_loc[4 * t + 2] = a.z;
        s_loc[4 * t + 3] = a.w;
    }
    __syncthreads();

    if (t < NPAIR) {
        int pe = 0, rem = t;
        while (rem >= NEXP - pe) { rem -= NEXP - pe; ++pe; }
        const int pf = pe + rem;
        float a = 0.f;
        #pragma unroll
        for (int dd = 0; dd < 16; ++dd)
            a += s_loc[dd] * reT[dd][pe] * reT[dd][pf];
        (ws + WS_GP)[j * NPAIR + t] = a;
    }
}

// ---------------------------------------------------------------------------
// Final: sum 64 partial Grams, norms from diagonal, clipped cosine mean.
// ---------------------------------------------------------------------------
__global__ __launch_bounds__(192) void moe_final(
    const float* __restrict__ ws,
    float* __restrict__ div_out)
{
    __shared__ float G[NPAIR];
    __shared__ float nr[NEXP];
    __shared__ float lsum;
    const int t = threadIdx.x;

    if (t == 0) lsum = 0.f;
    if (t < NPAIR) {
        const float* gp = ws + WS_GP;
        float g = 0.f;
        #pragma unroll 8
        for (int jj = 0; jj < NRED; ++jj) g += gp[jj * NPAIR + t];
        G[t] = g;
    }
    __syncthreads();
    if (t < NEXP) {
        int idx = t * NEXP - (t * (t - 1)) / 2;   // diagonal (t,t)
        nr[t] = fmaxf(sqrtf(G[idx]), 1e-8f);
    }
    __syncthreads();
    if (t < NPAIR) {
        int pe = 0, rem = t;
        while (rem >= NEXP - pe) { rem -= NEXP - pe; ++pe; }
        const int pf = pe + rem;
        if (pe != pf) {
            float sim = G[t] / (nr[pe] * nr[pf]);
            sim = fminf(1.f, fmaxf(-1.f, sim));
            atomicAdd(&lsum, 2.f * sim);
        }
    }
    __syncthreads();
    if (t == 0) *div_out = lsum / (float)(NEXP * (NEXP - 1)) * 0.1f;
}

extern "C" void kernel_launch(void* const* d_in, const int* in_sizes, int n_in,
                              void* d_out, int out_size, void* d_ws, size_t ws_size,
                              hipStream_t stream) {
    const float* x  = (const float*)d_in[0];
    const float* gw = (const float*)d_in[1];
    const float* gb = (const float*)d_in[2];
    const float* sh = (const float*)d_in[3];
    const float* re = (const float*)d_in[4];
    float* out = (float*)d_out;
    float* ws = (float*)d_ws;   // needs ~8.1 MB (arena 256 MiB)

    moe_fused<<<NBLK, 256, 0, stream>>>(x, gw, gb, sh, re, out, ws);
    moe_xred_gram<<<NRED, 256, 0, stream>>>(re, ws);
    moe_final<<<1, 192, 0, stream>>>(ws, out + (size_t)NTOK * DDIM);
}